// Round 12
// baseline (163.665 us; speedup 1.0000x reference)
//
#include <hip/hip_runtime.h>

#define HH 512
#define WW 512
#define TS 32
#define SQW 42
#define SQH 42
#define O1H 39
#define O1W 39
#define O2H 35
#define O2W 35

// d_ws float layout (all weights pre-transposed/pre-folded by prep kernel):
#define W2T 0     /* [tap9][ci3][c4]   108 */
#define W3T 108   /* [tap4][ci7][c8]   224 (o2cat sq-chans folded) */
#define W4T 332   /* [u15][c16]        240 (dup cat-chans folded)  */
#define B2O 572
#define B3O 576
#define B4O 584

// LDS-only phase barrier: orders LDS producer->consumer across waves WITHOUT
// draining the global-store queue (no vmcnt(0)). Stores stay in flight.
__device__ __forceinline__ void barrier_lds(void) {
    asm volatile("s_waitcnt lgkmcnt(0)" ::: "memory");
    __builtin_amdgcn_s_barrier();
    asm volatile("" ::: "memory");
}

__global__ void prep_weights(const float* __restrict__ w2, const float* __restrict__ b2,
                             const float* __restrict__ w3, const float* __restrict__ b3,
                             const float* __restrict__ w4, const float* __restrict__ b4,
                             float* __restrict__ ws)
{
    int t = threadIdx.x;
    if (t < 108) {
        int c = t & 3, ci = (t >> 2) % 3, tap = t / 12;
        int i = tap / 3, j = tap % 3;
        ws[W2T + t] = w2[((c*3+ci)*3+i)*3+j];
    }
    if (t < 224) {
        int c = t & 7, ci = (t >> 3) % 7, tap = t / 56;
        int i = tap >> 1, j = tap & 1;
        float v = w3[((c*8+ci)*2+i)*2+j];
        if (ci == 6) v += w3[((c*8+7)*2+i)*2+j];   // o2cat ch6,7 both = sq
        ws[W3T + t] = v;
    }
    if (t < 240) {
        int c = t & 15, u = t >> 4;
        float v;
        if (u < 12)       v = w4[c*20+u];
        else if (u == 12) v = w4[c*20+12] + w4[c*20+16];
        else if (u == 13) v = w4[c*20+13] + w4[c*20+17];
        else              v = w4[c*20+14] + w4[c*20+15] + w4[c*20+18] + w4[c*20+19];
        ws[W4T + t] = v;
    }
    if (t < 4)  ws[B2O + t] = b2[t];
    if (t < 8)  ws[B3O + t] = b3[t];
    if (t < 16) ws[B4O + t] = b4[t];
}

__global__ __launch_bounds__(256) void enc_fused(
    const float* __restrict__ f,
    const float* __restrict__ w1, const float* __restrict__ b1,
    const float* __restrict__ wf,   // folded weights in d_ws
    float* __restrict__ out)
{
    __shared__ __align__(16) float s_sq[SQH*SQW];
    __shared__ __align__(16) float s_o1[O1H*O1W*2];   // [h][w][c2]
    __shared__ __align__(16) float s_o2[O2H*O2W*4];   // [h][w][c4]

    const int tid = threadIdx.x;
    const int h0 = blockIdx.y * TS;
    const int w0 = blockIdx.x * TS;
    const size_t HWp = (size_t)HH*WW;

    const float PI = 3.14159265358979323846f;
    const float TWO_PI = 6.283185307179586477f;
    const float INV2PI = 0.15915494309189533577f;

    // Two tiles per block (batches bz and bz+4): iter-1 compute hides iter-0
    // stage-3 store drain. lgkm-only barriers keep stores in flight throughout.
    #pragma unroll 1
    for (int it = 0; it < 2; ++it) {
        const int b = blockIdx.z + 4*it;
        const float* fb = f + (size_t)b * (HH*WW);
        float* ob = out + (size_t)b*48*HWp;

        if (it) barrier_lds();   // prev-iter LDS reads done before s_sq overwrite

        // ---- phase 1: sq = wrapped vertical diff, squared ----
        #pragma unroll
        for (int p = 0; p < 7; ++p) {
            int idx = tid + 256*p;
            if (idx < SQH*SQW) {
                int rh = idx / SQW, rwp = idx % SQW;
                int gh = h0 + rh - 4, gw = w0 + rwp - 4;
                float v = 0.f;
                if (gh > 0 && gh < HH && gw >= 0 && gw < WW) {
                    float d = fb[gh*WW + gw] - fb[(gh-1)*WW + gw];
                    float dd = fmaf(-TWO_PI, floorf((d + PI) * INV2PI), d);
                    if (dd == -PI && d > 0.f) dd = PI;
                    float r = (fabsf(d) < PI) ? d : dd;
                    v = r * r;
                }
                s_sq[idx] = v;
            }
        }
        barrier_lds();

        // ---- store sq-dup channels (30,31,34,35,42,43,46,47) — transient ----
        {
            const int rws = tid & 31, qs = tid >> 5;
            #pragma unroll
            for (int k = 0; k < 4; ++k) {
                float v = s_sq[(qs + 8*k + 4)*SQW + rws + 4];
                float* o = ob + (size_t)(h0 + qs + 8*k)*WW + (w0 + rws);
                o[30*HWp]=v; o[31*HWp]=v; o[34*HWp]=v; o[35*HWp]=v;
                o[42*HWp]=v; o[43*HWp]=v; o[46*HWp]=v; o[47*HWp]=v;
            }
        }

        // ---- phase 2: o1 4x4 dil1 (pad l1/r2), 1ch -> 2ch; OOB -> 0 ----
        #pragma unroll
        for (int p = 0; p < 6; ++p) {
            int idx = tid + 256*p;
            if (idx < O1H*O1W) {
                int rh = idx / O1W, rwp = idx % O1W;
                float a0 = b1[0], a1 = b1[1];
                #pragma unroll
                for (int i = 0; i < 4; ++i)
                #pragma unroll
                for (int j = 0; j < 4; ++j) {
                    float x = s_sq[(rh+i)*SQW + rwp+j];
                    a0 += x * w1[i*4+j];
                    a1 += x * w1[16+i*4+j];
                }
                int gy = h0 + rh - 3, gx = w0 + rwp - 3;
                bool inimg = (gy >= 0) & (gy < HH) & (gx >= 0) & (gx < WW);
                float2 o; o.x = inimg ? a0 : 0.f; o.y = inimg ? a1 : 0.f;
                *(float2*)&s_o1[idx*2] = o;
            }
        }
        barrier_lds();

        // ---- store o1-dup channels (28,29,32,33,40,41,44,45) — transient ----
        {
            const int rws = tid & 31, qs = tid >> 5;
            #pragma unroll
            for (int k = 0; k < 4; ++k) {
                float2 t2 = *(const float2*)&s_o1[((qs + 8*k + 3)*O1W + rws + 3)*2];
                float* o = ob + (size_t)(h0 + qs + 8*k)*WW + (w0 + rws);
                o[28*HWp]=t2.x; o[29*HWp]=t2.y; o[32*HWp]=t2.x; o[33*HWp]=t2.y;
                o[40*HWp]=t2.x; o[41*HWp]=t2.y; o[44*HWp]=t2.x; o[45*HWp]=t2.y;
            }
        }

        // ---- phase 3: o2 3x3 dil2 (pad 2/2), 3ch -> 4ch; OOB -> 0 ----
        {
            int rh[5], rwp[5]; bool val[5], img[5];
            float acc[4][5];
            #pragma unroll
            for (int p = 0; p < 5; ++p) {
                int idx = tid + 256*p;
                val[p] = idx < O2H*O2W;
                int id = val[p] ? idx : 0;
                rh[p] = id / O2W; rwp[p] = id % O2W;
                int gy = h0 + rh[p] - 1, gx = w0 + rwp[p] - 1;
                img[p] = (gy >= 0) & (gy < HH) & (gx >= 0) & (gx < WW);
                #pragma unroll
                for (int c = 0; c < 4; ++c) acc[c][p] = wf[B2O + c];
            }
            #pragma unroll
            for (int i = 0; i < 3; ++i)
            #pragma unroll
            for (int j = 0; j < 3; ++j) {
                const float4 wa = *(const float4*)&wf[W2T + (i*3+j)*12];
                const float4 wb = *(const float4*)&wf[W2T + (i*3+j)*12 + 4];
                const float4 wc = *(const float4*)&wf[W2T + (i*3+j)*12 + 8];
                #pragma unroll
                for (int p = 0; p < 5; ++p) {
                    float2 xo = *(const float2*)&s_o1[((rh[p]+2*i)*O1W + rwp[p]+2*j)*2];
                    float  xs = s_sq[(rh[p]+1+2*i)*SQW + rwp[p]+1+2*j];
                    acc[0][p] += xo.x*wa.x + xo.y*wb.x + xs*wc.x;
                    acc[1][p] += xo.x*wa.y + xo.y*wb.y + xs*wc.y;
                    acc[2][p] += xo.x*wa.z + xo.y*wb.z + xs*wc.z;
                    acc[3][p] += xo.x*wa.w + xo.y*wb.w + xs*wc.w;
                }
            }
            #pragma unroll
            for (int p = 0; p < 5; ++p) if (val[p]) {
                float4 o;
                o.x = img[p] ? acc[0][p] : 0.f;
                o.y = img[p] ? acc[1][p] : 0.f;
                o.z = img[p] ? acc[2][p] : 0.f;
                o.w = img[p] ? acc[3][p] : 0.f;
                *(float4*)&s_o2[(rh[p]*O2W + rwp[p])*4] = o;
            }
        }
        barrier_lds();

        // ---- store o2-dup channels (24-27, 36-39) — transient ----
        {
            const int rws = tid & 31, qs = tid >> 5;
            #pragma unroll
            for (int k = 0; k < 4; ++k) {
                float4 t4 = *(const float4*)&s_o2[((qs + 8*k + 1)*O2W + rws + 1)*4];
                float* o = ob + (size_t)(h0 + qs + 8*k)*WW + (w0 + rws);
                o[24*HWp]=t4.x; o[25*HWp]=t4.y; o[26*HWp]=t4.z; o[27*HWp]=t4.w;
                o[36*HWp]=t4.x; o[37*HWp]=t4.y; o[38*HWp]=t4.z; o[39*HWp]=t4.w;
            }
        }

        // ---- stage 3: o3 + store ch16-23, o4 + store ch0-15 ----
        {
            const int rw = tid & 31;
            const int q  = tid >> 5;
            int pofs[4];
            #pragma unroll
            for (int k = 0; k < 4; ++k) pofs[k] = (h0 + q + 8*k)*WW + (w0 + rw);

            float sqv[4], o1v[2][4], o2v[4][4], o3v[8][4];
            #pragma unroll
            for (int k = 0; k < 4; ++k) {
                int rh = q + 8*k;
                sqv[k] = s_sq[(rh+4)*SQW + rw+4];
                float2 t2 = *(const float2*)&s_o1[((rh+3)*O1W + rw+3)*2];
                o1v[0][k]=t2.x; o1v[1][k]=t2.y;
                float4 t4 = *(const float4*)&s_o2[((rh+1)*O2W + rw+1)*4];
                o2v[0][k]=t4.x; o2v[1][k]=t4.y; o2v[2][k]=t4.z; o2v[3][k]=t4.w;
            }

            #pragma unroll
            for (int c = 0; c < 8; ++c) {
                float bv = wf[B3O + c];
                #pragma unroll
                for (int k = 0; k < 4; ++k) o3v[c][k] = bv;
            }
            #pragma unroll
            for (int i = 0; i < 2; ++i)
            #pragma unroll
            for (int j = 0; j < 2; ++j) {
                float xin[7][4];
                #pragma unroll
                for (int k = 0; k < 4; ++k) {
                    int hh = q + 8*k + 3*i, ww = rw + 3*j;
                    float4 a = *(const float4*)&s_o2[(hh*O2W+ww)*4];
                    xin[0][k]=a.x; xin[1][k]=a.y; xin[2][k]=a.z; xin[3][k]=a.w;
                    float2 bq = *(const float2*)&s_o1[((hh+2)*O1W + ww+2)*2];
                    xin[4][k]=bq.x; xin[5][k]=bq.y;
                    xin[6][k]=s_sq[(hh+3)*SQW + ww+3];
                }
                #pragma unroll
                for (int ci = 0; ci < 7; ++ci) {
                    float4 wa = *(const float4*)&wf[W3T + (i*2+j)*56 + ci*8];
                    float4 wb = *(const float4*)&wf[W3T + (i*2+j)*56 + ci*8 + 4];
                    #pragma unroll
                    for (int k = 0; k < 4; ++k) {
                        float x = xin[ci][k];
                        o3v[0][k] += x*wa.x; o3v[1][k] += x*wa.y;
                        o3v[2][k] += x*wa.z; o3v[3][k] += x*wa.w;
                        o3v[4][k] += x*wb.x; o3v[5][k] += x*wb.y;
                        o3v[6][k] += x*wb.z; o3v[7][k] += x*wb.w;
                    }
                }
            }
            #pragma unroll
            for (int k = 0; k < 4; ++k) {
                float* o = ob + pofs[k];
                #pragma unroll
                for (int c = 0; c < 8; ++c) o[(size_t)(16+c)*HWp] = o3v[c][k];
            }

            #pragma unroll
            for (int cg = 0; cg < 4; ++cg) {
                float acc[4][4];
                #pragma unroll
                for (int c = 0; c < 4; ++c) {
                    float bv = wf[B4O + cg*4 + c];
                    #pragma unroll
                    for (int k = 0; k < 4; ++k) acc[c][k] = bv;
                }
                #pragma unroll
                for (int u = 0; u < 15; ++u) {
                    float4 wv = *(const float4*)&wf[W4T + u*16 + cg*4];
                    #pragma unroll
                    for (int k = 0; k < 4; ++k) {
                        float x = (u<8) ? o3v[u][k] : (u<12) ? o2v[u-8][k]
                                : (u<14) ? o1v[u-12][k] : sqv[k];
                        acc[0][k]+=x*wv.x; acc[1][k]+=x*wv.y;
                        acc[2][k]+=x*wv.z; acc[3][k]+=x*wv.w;
                    }
                }
                #pragma unroll
                for (int c = 0; c < 4; ++c)
                #pragma unroll
                for (int k = 0; k < 4; ++k)
                    ob[(size_t)(cg*4+c)*HWp + pofs[k]] = acc[c][k];
            }
        }
    }
}

extern "C" void kernel_launch(void* const* d_in, const int* in_sizes, int n_in,
                              void* d_out, int out_size, void* d_ws, size_t ws_size,
                              hipStream_t stream) {
    const float* f  = (const float*)d_in[0];
    const float* w1 = (const float*)d_in[1];
    const float* b1 = (const float*)d_in[2];
    const float* w2 = (const float*)d_in[3];
    const float* b2 = (const float*)d_in[4];
    const float* w3 = (const float*)d_in[5];
    const float* b3 = (const float*)d_in[6];
    const float* w4 = (const float*)d_in[7];
    const float* b4 = (const float*)d_in[8];
    float* out = (float*)d_out;
    float* ws  = (float*)d_ws;

    prep_weights<<<1, 256, 0, stream>>>(w2, b2, w3, b3, w4, b4, ws);
    dim3 grid(WW/TS, HH/TS, 4);
    enc_fused<<<grid, 256, 0, stream>>>(f, w1, b1, ws, out);
}

// Round 13
// 99.583 us; speedup vs baseline: 1.6435x; 1.6435x over previous
//
#include <hip/hip_runtime.h>

#define HH 512
#define WW 512
#define TS 32
#define SQW 42
#define SQH 42
#define O1H 39
#define O1W 39
#define O2H 35
#define O2W 35

// d_ws float layout (all weights pre-transposed/pre-folded by prep kernel):
#define W2T 0     /* [tap9][ci3][c4]   108 */
#define W3T 108   /* [tap4][ci7][c8]   224 (o2cat sq-chans folded) */
#define W4T 332   /* [u15][c16]        240 (dup cat-chans folded)  */
#define B2O 572
#define B3O 576
#define B4O 584

__global__ void prep_weights(const float* __restrict__ w2, const float* __restrict__ b2,
                             const float* __restrict__ w3, const float* __restrict__ b3,
                             const float* __restrict__ w4, const float* __restrict__ b4,
                             float* __restrict__ ws)
{
    int t = threadIdx.x;
    if (t < 108) {
        int c = t & 3, ci = (t >> 2) % 3, tap = t / 12;
        int i = tap / 3, j = tap % 3;
        ws[W2T + t] = w2[((c*3+ci)*3+i)*3+j];
    }
    if (t < 224) {
        int c = t & 7, ci = (t >> 3) % 7, tap = t / 56;
        int i = tap >> 1, j = tap & 1;
        float v = w3[((c*8+ci)*2+i)*2+j];
        if (ci == 6) v += w3[((c*8+7)*2+i)*2+j];   // o2cat ch6,7 both = sq
        ws[W3T + t] = v;
    }
    if (t < 240) {
        int c = t & 15, u = t >> 4;
        float v;
        if (u < 12)       v = w4[c*20+u];
        else if (u == 12) v = w4[c*20+12] + w4[c*20+16];
        else if (u == 13) v = w4[c*20+13] + w4[c*20+17];
        else              v = w4[c*20+14] + w4[c*20+15] + w4[c*20+18] + w4[c*20+19];
        ws[W4T + t] = v;
    }
    if (t < 4)  ws[B2O + t] = b2[t];
    if (t < 8)  ws[B3O + t] = b3[t];
    if (t < 16) ws[B4O + t] = b4[t];
}

__global__ __launch_bounds__(256) void enc_fused(
    const float* __restrict__ f,
    const float* __restrict__ w1, const float* __restrict__ b1,
    const float* __restrict__ wf,   // folded weights in d_ws
    float* __restrict__ out)
{
    __shared__ __align__(16) float s_sq[SQH*SQW];
    __shared__ __align__(16) float s_o1[O1H*O1W*2];   // [h][w][c2]
    __shared__ __align__(16) float s_o2[O2H*O2W*4];   // [h][w][c4]

    const int tid = threadIdx.x;
    const int b  = blockIdx.z;
    const int h0 = blockIdx.y * TS;
    const int w0 = blockIdx.x * TS;
    const size_t HWp = (size_t)HH*WW;
    // parity: mixes within a CU's resident set -> staggered store phases
    const bool early = ((blockIdx.x ^ blockIdx.y ^ blockIdx.z) & 1) == 0;

    // ---- phase 1: sq = wrapped vertical diff, squared (floor-mod == jnp.mod) ----
    const float* fb = f + (size_t)b * (HH*WW);
    const float PI = 3.14159265358979323846f;
    const float TWO_PI = 6.283185307179586477f;
    const float INV2PI = 0.15915494309189533577f;
    #pragma unroll
    for (int p = 0; p < 7; ++p) {
        int idx = tid + 256*p;
        if (idx < SQH*SQW) {
            int rh = idx / SQW, rwp = idx % SQW;
            int gh = h0 + rh - 4, gw = w0 + rwp - 4;
            float v = 0.f;
            if (gh > 0 && gh < HH && gw >= 0 && gw < WW) {
                float d = fb[gh*WW + gw] - fb[(gh-1)*WW + gw];
                float dd = fmaf(-TWO_PI, floorf((d + PI) * INV2PI), d); // mod(d+pi,2pi)-pi
                if (dd == -PI && d > 0.f) dd = PI;
                float r = (fabsf(d) < PI) ? d : dd;
                v = r * r;
            }
            s_sq[idx] = v;
        }
    }
    __syncthreads();

    // ---- store sq-dup channels (30,31,34,35,42,43,46,47) — transient, even blocks ----
    if (early) {
        const int rws = tid & 31, qs = tid >> 5;
        #pragma unroll
        for (int k = 0; k < 4; ++k) {
            float v = s_sq[(qs + 8*k + 4)*SQW + rws + 4];
            float* o = out + (size_t)b*48*HWp + (size_t)(h0 + qs + 8*k)*WW + (w0 + rws);
            o[30*HWp]=v; o[31*HWp]=v; o[34*HWp]=v; o[35*HWp]=v;
            o[42*HWp]=v; o[43*HWp]=v; o[46*HWp]=v; o[47*HWp]=v;
        }
    }

    // ---- phase 2: o1 4x4 dil1 (pad l1/r2), 1ch -> 2ch; OOB -> 0 ----
    #pragma unroll
    for (int p = 0; p < 6; ++p) {
        int idx = tid + 256*p;
        if (idx < O1H*O1W) {
            int rh = idx / O1W, rwp = idx % O1W;
            float a0 = b1[0], a1 = b1[1];
            #pragma unroll
            for (int i = 0; i < 4; ++i)
            #pragma unroll
            for (int j = 0; j < 4; ++j) {
                float x = s_sq[(rh+i)*SQW + rwp+j];
                a0 += x * w1[i*4+j];
                a1 += x * w1[16+i*4+j];
            }
            int gy = h0 + rh - 3, gx = w0 + rwp - 3;
            bool inimg = (gy >= 0) & (gy < HH) & (gx >= 0) & (gx < WW);
            float2 o; o.x = inimg ? a0 : 0.f; o.y = inimg ? a1 : 0.f;
            *(float2*)&s_o1[idx*2] = o;
        }
    }
    __syncthreads();

    // ---- store o1-dup channels (28,29,32,33,40,41,44,45) — transient, even blocks ----
    if (early) {
        const int rws = tid & 31, qs = tid >> 5;
        #pragma unroll
        for (int k = 0; k < 4; ++k) {
            float2 t2 = *(const float2*)&s_o1[((qs + 8*k + 3)*O1W + rws + 3)*2];
            float* o = out + (size_t)b*48*HWp + (size_t)(h0 + qs + 8*k)*WW + (w0 + rws);
            o[28*HWp]=t2.x; o[29*HWp]=t2.y; o[32*HWp]=t2.x; o[33*HWp]=t2.y;
            o[40*HWp]=t2.x; o[41*HWp]=t2.y; o[44*HWp]=t2.x; o[45*HWp]=t2.y;
        }
    }

    // ---- phase 3: o2 3x3 dil2 (pad 2/2), 3ch -> 4ch; OOB -> 0 ----
    {
        int rh[5], rwp[5]; bool val[5], img[5];
        float acc[4][5];
        #pragma unroll
        for (int p = 0; p < 5; ++p) {
            int idx = tid + 256*p;
            val[p] = idx < O2H*O2W;
            int id = val[p] ? idx : 0;
            rh[p] = id / O2W; rwp[p] = id % O2W;
            int gy = h0 + rh[p] - 1, gx = w0 + rwp[p] - 1;
            img[p] = (gy >= 0) & (gy < HH) & (gx >= 0) & (gx < WW);
            #pragma unroll
            for (int c = 0; c < 4; ++c) acc[c][p] = wf[B2O + c];
        }
        #pragma unroll
        for (int i = 0; i < 3; ++i)
        #pragma unroll
        for (int j = 0; j < 3; ++j) {
            const float4 wa = *(const float4*)&wf[W2T + (i*3+j)*12];
            const float4 wb = *(const float4*)&wf[W2T + (i*3+j)*12 + 4];
            const float4 wc = *(const float4*)&wf[W2T + (i*3+j)*12 + 8];
            #pragma unroll
            for (int p = 0; p < 5; ++p) {
                float2 xo = *(const float2*)&s_o1[((rh[p]+2*i)*O1W + rwp[p]+2*j)*2];
                float  xs = s_sq[(rh[p]+1+2*i)*SQW + rwp[p]+1+2*j];
                acc[0][p] += xo.x*wa.x + xo.y*wb.x + xs*wc.x;
                acc[1][p] += xo.x*wa.y + xo.y*wb.y + xs*wc.y;
                acc[2][p] += xo.x*wa.z + xo.y*wb.z + xs*wc.z;
                acc[3][p] += xo.x*wa.w + xo.y*wb.w + xs*wc.w;
            }
        }
        #pragma unroll
        for (int p = 0; p < 5; ++p) if (val[p]) {
            float4 o;
            o.x = img[p] ? acc[0][p] : 0.f;
            o.y = img[p] ? acc[1][p] : 0.f;
            o.z = img[p] ? acc[2][p] : 0.f;
            o.w = img[p] ? acc[3][p] : 0.f;
            *(float4*)&s_o2[(rh[p]*O2W + rwp[p])*4] = o;
        }
    }
    __syncthreads();

    // ---- store o2-dup channels (24-27, 36-39) — transient, even blocks ----
    if (early) {
        const int rws = tid & 31, qs = tid >> 5;
        #pragma unroll
        for (int k = 0; k < 4; ++k) {
            float4 t4 = *(const float4*)&s_o2[((qs + 8*k + 1)*O2W + rws + 1)*4];
            float* o = out + (size_t)b*48*HWp + (size_t)(h0 + qs + 8*k)*WW + (w0 + rws);
            o[24*HWp]=t4.x; o[25*HWp]=t4.y; o[26*HWp]=t4.z; o[27*HWp]=t4.w;
            o[36*HWp]=t4.x; o[37*HWp]=t4.y; o[38*HWp]=t4.z; o[39*HWp]=t4.w;
        }
    }

    // ---- stage 3: o3 + store ch16-23, o4 + store ch0-15 (R5/R11 structure) ----
    {
        const int rw = tid & 31;
        const int q  = tid >> 5;
        float* ob = out + (size_t)b*48*HWp;
        int pofs[4];
        #pragma unroll
        for (int k = 0; k < 4; ++k) pofs[k] = (h0 + q + 8*k)*WW + (w0 + rw);

        float sqv[4], o1v[2][4], o2v[4][4], o3v[8][4];
        #pragma unroll
        for (int k = 0; k < 4; ++k) {
            int rh = q + 8*k;
            sqv[k] = s_sq[(rh+4)*SQW + rw+4];
            float2 t2 = *(const float2*)&s_o1[((rh+3)*O1W + rw+3)*2];
            o1v[0][k]=t2.x; o1v[1][k]=t2.y;
            float4 t4 = *(const float4*)&s_o2[((rh+1)*O2W + rw+1)*4];
            o2v[0][k]=t4.x; o2v[1][k]=t4.y; o2v[2][k]=t4.z; o2v[3][k]=t4.w;
        }

        // o3: 2x2 dil3 (pad 1/2), 7 unique ci -> 8 co
        #pragma unroll
        for (int c = 0; c < 8; ++c) {
            float bv = wf[B3O + c];
            #pragma unroll
            for (int k = 0; k < 4; ++k) o3v[c][k] = bv;
        }
        #pragma unroll
        for (int i = 0; i < 2; ++i)
        #pragma unroll
        for (int j = 0; j < 2; ++j) {
            float xin[7][4];
            #pragma unroll
            for (int k = 0; k < 4; ++k) {
                int hh = q + 8*k + 3*i, ww = rw + 3*j;
                float4 a = *(const float4*)&s_o2[(hh*O2W+ww)*4];
                xin[0][k]=a.x; xin[1][k]=a.y; xin[2][k]=a.z; xin[3][k]=a.w;
                float2 bq = *(const float2*)&s_o1[((hh+2)*O1W + ww+2)*2];
                xin[4][k]=bq.x; xin[5][k]=bq.y;
                xin[6][k]=s_sq[(hh+3)*SQW + ww+3];
            }
            #pragma unroll
            for (int ci = 0; ci < 7; ++ci) {
                float4 wa = *(const float4*)&wf[W3T + (i*2+j)*56 + ci*8];
                float4 wb = *(const float4*)&wf[W3T + (i*2+j)*56 + ci*8 + 4];
                #pragma unroll
                for (int k = 0; k < 4; ++k) {
                    float x = xin[ci][k];
                    o3v[0][k] += x*wa.x; o3v[1][k] += x*wa.y;
                    o3v[2][k] += x*wa.z; o3v[3][k] += x*wa.w;
                    o3v[4][k] += x*wb.x; o3v[5][k] += x*wb.y;
                    o3v[6][k] += x*wb.z; o3v[7][k] += x*wb.w;
                }
            }
        }
        #pragma unroll
        for (int k = 0; k < 4; ++k) {
            float* o = ob + pofs[k];
            #pragma unroll
            for (int c = 0; c < 8; ++c) o[(size_t)(16+c)*HWp] = o3v[c][k];
        }

        // o4: 1x1, 15 unique inputs -> 16 co
        #pragma unroll
        for (int cg = 0; cg < 4; ++cg) {
            float acc[4][4];
            #pragma unroll
            for (int c = 0; c < 4; ++c) {
                float bv = wf[B4O + cg*4 + c];
                #pragma unroll
                for (int k = 0; k < 4; ++k) acc[c][k] = bv;
            }
            #pragma unroll
            for (int u = 0; u < 15; ++u) {
                float4 wv = *(const float4*)&wf[W4T + u*16 + cg*4];
                #pragma unroll
                for (int k = 0; k < 4; ++k) {
                    float x = (u<8) ? o3v[u][k] : (u<12) ? o2v[u-8][k]
                            : (u<14) ? o1v[u-12][k] : sqv[k];
                    acc[0][k]+=x*wv.x; acc[1][k]+=x*wv.y;
                    acc[2][k]+=x*wv.z; acc[3][k]+=x*wv.w;
                }
            }
            #pragma unroll
            for (int c = 0; c < 4; ++c)
            #pragma unroll
            for (int k = 0; k < 4; ++k)
                ob[(size_t)(cg*4+c)*HWp + pofs[k]] = acc[c][k];
        }
    }

    // ---- odd blocks: all dup channels stored at the END (LDS still valid) ----
    if (!early) {
        const int rws = tid & 31, qs = tid >> 5;
        #pragma unroll
        for (int k = 0; k < 4; ++k) {
            float  v  = s_sq[(qs + 8*k + 4)*SQW + rws + 4];
            float2 t2 = *(const float2*)&s_o1[((qs + 8*k + 3)*O1W + rws + 3)*2];
            float4 t4 = *(const float4*)&s_o2[((qs + 8*k + 1)*O2W + rws + 1)*4];
            float* o = out + (size_t)b*48*HWp + (size_t)(h0 + qs + 8*k)*WW + (w0 + rws);
            o[24*HWp]=t4.x; o[25*HWp]=t4.y; o[26*HWp]=t4.z; o[27*HWp]=t4.w;
            o[28*HWp]=t2.x; o[29*HWp]=t2.y; o[30*HWp]=v;    o[31*HWp]=v;
            o[32*HWp]=t2.x; o[33*HWp]=t2.y; o[34*HWp]=v;    o[35*HWp]=v;
            o[36*HWp]=t4.x; o[37*HWp]=t4.y; o[38*HWp]=t4.z; o[39*HWp]=t4.w;
            o[40*HWp]=t2.x; o[41*HWp]=t2.y; o[42*HWp]=v;    o[43*HWp]=v;
            o[44*HWp]=t2.x; o[45*HWp]=t2.y; o[46*HWp]=v;    o[47*HWp]=v;
        }
    }
}

extern "C" void kernel_launch(void* const* d_in, const int* in_sizes, int n_in,
                              void* d_out, int out_size, void* d_ws, size_t ws_size,
                              hipStream_t stream) {
    const float* f  = (const float*)d_in[0];
    const float* w1 = (const float*)d_in[1];
    const float* b1 = (const float*)d_in[2];
    const float* w2 = (const float*)d_in[3];
    const float* b2 = (const float*)d_in[4];
    const float* w3 = (const float*)d_in[5];
    const float* b3 = (const float*)d_in[6];
    const float* w4 = (const float*)d_in[7];
    const float* b4 = (const float*)d_in[8];
    float* out = (float*)d_out;
    float* ws  = (float*)d_ws;

    prep_weights<<<1, 256, 0, stream>>>(w2, b2, w3, b3, w4, b4, ws);
    dim3 grid(WW/TS, HH/TS, 8);
    enc_fused<<<grid, 256, 0, stream>>>(f, w1, b1, ws, out);
}

// Round 14
// 84.009 us; speedup vs baseline: 1.9482x; 1.1854x over previous
//
#include <hip/hip_runtime.h>

#define HH 512
#define WW 512
#define TS 32
#define SQW 42
#define SQH 42
#define O1H 39
#define O1W 39
#define O2H 35
#define O2W 35

// d_ws float layout (all weights pre-transposed/pre-folded by prep kernel):
#define W2T 0     /* [tap9][ci3][c4]   108 */
#define W3T 108   /* [tap4][ci7][c8]   224 (o2cat sq-chans folded) */
#define W4T 332   /* [u15][c16]        240 (dup cat-chans folded)  */
#define B2O 572
#define B3O 576
#define B4O 584

// Streaming (non-temporal) store: no L2 allocate for write-once output.
template <typename T>
__device__ __forceinline__ void st_nt(T* p, T v) { __builtin_nontemporal_store(v, p); }

__global__ void prep_weights(const float* __restrict__ w2, const float* __restrict__ b2,
                             const float* __restrict__ w3, const float* __restrict__ b3,
                             const float* __restrict__ w4, const float* __restrict__ b4,
                             float* __restrict__ ws)
{
    int t = threadIdx.x;
    if (t < 108) {
        int c = t & 3, ci = (t >> 2) % 3, tap = t / 12;
        int i = tap / 3, j = tap % 3;
        ws[W2T + t] = w2[((c*3+ci)*3+i)*3+j];
    }
    if (t < 224) {
        int c = t & 7, ci = (t >> 3) % 7, tap = t / 56;
        int i = tap >> 1, j = tap & 1;
        float v = w3[((c*8+ci)*2+i)*2+j];
        if (ci == 6) v += w3[((c*8+7)*2+i)*2+j];   // o2cat ch6,7 both = sq
        ws[W3T + t] = v;
    }
    if (t < 240) {
        int c = t & 15, u = t >> 4;
        float v;
        if (u < 12)       v = w4[c*20+u];
        else if (u == 12) v = w4[c*20+12] + w4[c*20+16];
        else if (u == 13) v = w4[c*20+13] + w4[c*20+17];
        else              v = w4[c*20+14] + w4[c*20+15] + w4[c*20+18] + w4[c*20+19];
        ws[W4T + t] = v;
    }
    if (t < 4)  ws[B2O + t] = b2[t];
    if (t < 8)  ws[B3O + t] = b3[t];
    if (t < 16) ws[B4O + t] = b4[t];
}

__global__ __launch_bounds__(256) void enc_fused(
    const float* __restrict__ f,
    const float* __restrict__ w1, const float* __restrict__ b1,
    const float* __restrict__ wf,   // folded weights in d_ws
    float* __restrict__ out)
{
    __shared__ __align__(16) float s_sq[SQH*SQW];
    __shared__ __align__(16) float s_o1[O1H*O1W*2];   // [h][w][c2]
    __shared__ __align__(16) float s_o2[O2H*O2W*4];   // [h][w][c4]

    const int tid = threadIdx.x;
    const int b  = blockIdx.z;
    const int h0 = blockIdx.y * TS;
    const int w0 = blockIdx.x * TS;
    const size_t HWp = (size_t)HH*WW;

    // ---- phase 1: sq = wrapped vertical diff, squared (floor-mod == jnp.mod) ----
    const float* fb = f + (size_t)b * (HH*WW);
    const float PI = 3.14159265358979323846f;
    const float TWO_PI = 6.283185307179586477f;
    const float INV2PI = 0.15915494309189533577f;
    #pragma unroll
    for (int p = 0; p < 7; ++p) {
        int idx = tid + 256*p;
        if (idx < SQH*SQW) {
            int rh = idx / SQW, rwp = idx % SQW;
            int gh = h0 + rh - 4, gw = w0 + rwp - 4;
            float v = 0.f;
            if (gh > 0 && gh < HH && gw >= 0 && gw < WW) {
                float d = fb[gh*WW + gw] - fb[(gh-1)*WW + gw];
                float dd = fmaf(-TWO_PI, floorf((d + PI) * INV2PI), d); // mod(d+pi,2pi)-pi
                if (dd == -PI && d > 0.f) dd = PI;
                float r = (fabsf(d) < PI) ? d : dd;
                v = r * r;
            }
            s_sq[idx] = v;
        }
    }
    __syncthreads();

    // ---- store sq-dup channels (30,31,34,35,42,43,46,47) — fully transient ----
    {
        const int rws = tid & 31, qs = tid >> 5;
        #pragma unroll
        for (int k = 0; k < 4; ++k) {
            float v = s_sq[(qs + 8*k + 4)*SQW + rws + 4];
            float* o = out + (size_t)b*48*HWp + (size_t)(h0 + qs + 8*k)*WW + (w0 + rws);
            st_nt(&o[30*HWp], v); st_nt(&o[31*HWp], v);
            st_nt(&o[34*HWp], v); st_nt(&o[35*HWp], v);
            st_nt(&o[42*HWp], v); st_nt(&o[43*HWp], v);
            st_nt(&o[46*HWp], v); st_nt(&o[47*HWp], v);
        }
    }

    // ---- phase 2: o1 4x4 dil1 (pad l1/r2), 1ch -> 2ch; OOB -> 0 ----
    #pragma unroll
    for (int p = 0; p < 6; ++p) {
        int idx = tid + 256*p;
        if (idx < O1H*O1W) {
            int rh = idx / O1W, rwp = idx % O1W;
            float a0 = b1[0], a1 = b1[1];
            #pragma unroll
            for (int i = 0; i < 4; ++i)
            #pragma unroll
            for (int j = 0; j < 4; ++j) {
                float x = s_sq[(rh+i)*SQW + rwp+j];
                a0 += x * w1[i*4+j];
                a1 += x * w1[16+i*4+j];
            }
            int gy = h0 + rh - 3, gx = w0 + rwp - 3;
            bool inimg = (gy >= 0) & (gy < HH) & (gx >= 0) & (gx < WW);
            float2 o; o.x = inimg ? a0 : 0.f; o.y = inimg ? a1 : 0.f;
            *(float2*)&s_o1[idx*2] = o;
        }
    }
    __syncthreads();

    // ---- store o1-dup channels (28,29,32,33,40,41,44,45) — fully transient ----
    {
        const int rws = tid & 31, qs = tid >> 5;
        #pragma unroll
        for (int k = 0; k < 4; ++k) {
            float2 t2 = *(const float2*)&s_o1[((qs + 8*k + 3)*O1W + rws + 3)*2];
            float* o = out + (size_t)b*48*HWp + (size_t)(h0 + qs + 8*k)*WW + (w0 + rws);
            st_nt(&o[28*HWp], t2.x); st_nt(&o[29*HWp], t2.y);
            st_nt(&o[32*HWp], t2.x); st_nt(&o[33*HWp], t2.y);
            st_nt(&o[40*HWp], t2.x); st_nt(&o[41*HWp], t2.y);
            st_nt(&o[44*HWp], t2.x); st_nt(&o[45*HWp], t2.y);
        }
    }

    // ---- phase 3: o2 3x3 dil2 (pad 2/2), 3ch -> 4ch; OOB -> 0 ----
    {
        int rh[5], rwp[5]; bool val[5], img[5];
        float acc[4][5];
        #pragma unroll
        for (int p = 0; p < 5; ++p) {
            int idx = tid + 256*p;
            val[p] = idx < O2H*O2W;
            int id = val[p] ? idx : 0;
            rh[p] = id / O2W; rwp[p] = id % O2W;
            int gy = h0 + rh[p] - 1, gx = w0 + rwp[p] - 1;
            img[p] = (gy >= 0) & (gy < HH) & (gx >= 0) & (gx < WW);
            #pragma unroll
            for (int c = 0; c < 4; ++c) acc[c][p] = wf[B2O + c];
        }
        #pragma unroll
        for (int i = 0; i < 3; ++i)
        #pragma unroll
        for (int j = 0; j < 3; ++j) {
            const float4 wa = *(const float4*)&wf[W2T + (i*3+j)*12];
            const float4 wb = *(const float4*)&wf[W2T + (i*3+j)*12 + 4];
            const float4 wc = *(const float4*)&wf[W2T + (i*3+j)*12 + 8];
            #pragma unroll
            for (int p = 0; p < 5; ++p) {
                float2 xo = *(const float2*)&s_o1[((rh[p]+2*i)*O1W + rwp[p]+2*j)*2];
                float  xs = s_sq[(rh[p]+1+2*i)*SQW + rwp[p]+1+2*j];
                acc[0][p] += xo.x*wa.x + xo.y*wb.x + xs*wc.x;
                acc[1][p] += xo.x*wa.y + xo.y*wb.y + xs*wc.y;
                acc[2][p] += xo.x*wa.z + xo.y*wb.z + xs*wc.z;
                acc[3][p] += xo.x*wa.w + xo.y*wb.w + xs*wc.w;
            }
        }
        #pragma unroll
        for (int p = 0; p < 5; ++p) if (val[p]) {
            float4 o;
            o.x = img[p] ? acc[0][p] : 0.f;
            o.y = img[p] ? acc[1][p] : 0.f;
            o.z = img[p] ? acc[2][p] : 0.f;
            o.w = img[p] ? acc[3][p] : 0.f;
            *(float4*)&s_o2[(rh[p]*O2W + rwp[p])*4] = o;
        }
    }
    __syncthreads();

    // ---- store o2-dup channels (24-27, 36-39) — fully transient ----
    {
        const int rws = tid & 31, qs = tid >> 5;
        #pragma unroll
        for (int k = 0; k < 4; ++k) {
            float4 t4 = *(const float4*)&s_o2[((qs + 8*k + 1)*O2W + rws + 1)*4];
            float* o = out + (size_t)b*48*HWp + (size_t)(h0 + qs + 8*k)*WW + (w0 + rws);
            st_nt(&o[24*HWp], t4.x); st_nt(&o[25*HWp], t4.y);
            st_nt(&o[26*HWp], t4.z); st_nt(&o[27*HWp], t4.w);
            st_nt(&o[36*HWp], t4.x); st_nt(&o[37*HWp], t4.y);
            st_nt(&o[38*HWp], t4.z); st_nt(&o[39*HWp], t4.w);
        }
    }

    // ---- stage 3: o3 + store ch16-23, o4 + store ch0-15 (R11 structure) ----
    {
        const int rw = tid & 31;
        const int q  = tid >> 5;
        float* ob = out + (size_t)b*48*HWp;
        int pofs[4];
        #pragma unroll
        for (int k = 0; k < 4; ++k) pofs[k] = (h0 + q + 8*k)*WW + (w0 + rw);

        float sqv[4], o1v[2][4], o2v[4][4], o3v[8][4];
        #pragma unroll
        for (int k = 0; k < 4; ++k) {
            int rh = q + 8*k;
            sqv[k] = s_sq[(rh+4)*SQW + rw+4];
            float2 t2 = *(const float2*)&s_o1[((rh+3)*O1W + rw+3)*2];
            o1v[0][k]=t2.x; o1v[1][k]=t2.y;
            float4 t4 = *(const float4*)&s_o2[((rh+1)*O2W + rw+1)*4];
            o2v[0][k]=t4.x; o2v[1][k]=t4.y; o2v[2][k]=t4.z; o2v[3][k]=t4.w;
        }

        // o3: 2x2 dil3 (pad 1/2), 7 unique ci -> 8 co
        #pragma unroll
        for (int c = 0; c < 8; ++c) {
            float bv = wf[B3O + c];
            #pragma unroll
            for (int k = 0; k < 4; ++k) o3v[c][k] = bv;
        }
        #pragma unroll
        for (int i = 0; i < 2; ++i)
        #pragma unroll
        for (int j = 0; j < 2; ++j) {
            float xin[7][4];
            #pragma unroll
            for (int k = 0; k < 4; ++k) {
                int hh = q + 8*k + 3*i, ww = rw + 3*j;
                float4 a = *(const float4*)&s_o2[(hh*O2W+ww)*4];
                xin[0][k]=a.x; xin[1][k]=a.y; xin[2][k]=a.z; xin[3][k]=a.w;
                float2 bq = *(const float2*)&s_o1[((hh+2)*O1W + ww+2)*2];
                xin[4][k]=bq.x; xin[5][k]=bq.y;
                xin[6][k]=s_sq[(hh+3)*SQW + ww+3];
            }
            #pragma unroll
            for (int ci = 0; ci < 7; ++ci) {
                float4 wa = *(const float4*)&wf[W3T + (i*2+j)*56 + ci*8];
                float4 wb = *(const float4*)&wf[W3T + (i*2+j)*56 + ci*8 + 4];
                #pragma unroll
                for (int k = 0; k < 4; ++k) {
                    float x = xin[ci][k];
                    o3v[0][k] += x*wa.x; o3v[1][k] += x*wa.y;
                    o3v[2][k] += x*wa.z; o3v[3][k] += x*wa.w;
                    o3v[4][k] += x*wb.x; o3v[5][k] += x*wb.y;
                    o3v[6][k] += x*wb.z; o3v[7][k] += x*wb.w;
                }
            }
        }
        #pragma unroll
        for (int k = 0; k < 4; ++k) {
            float* o = ob + pofs[k];
            #pragma unroll
            for (int c = 0; c < 8; ++c) st_nt(&o[(size_t)(16+c)*HWp], o3v[c][k]);
        }

        // o4: 1x1, 15 unique inputs -> 16 co
        #pragma unroll
        for (int cg = 0; cg < 4; ++cg) {
            float acc[4][4];
            #pragma unroll
            for (int c = 0; c < 4; ++c) {
                float bv = wf[B4O + cg*4 + c];
                #pragma unroll
                for (int k = 0; k < 4; ++k) acc[c][k] = bv;
            }
            #pragma unroll
            for (int u = 0; u < 15; ++u) {
                float4 wv = *(const float4*)&wf[W4T + u*16 + cg*4];
                #pragma unroll
                for (int k = 0; k < 4; ++k) {
                    float x = (u<8) ? o3v[u][k] : (u<12) ? o2v[u-8][k]
                            : (u<14) ? o1v[u-12][k] : sqv[k];
                    acc[0][k]+=x*wv.x; acc[1][k]+=x*wv.y;
                    acc[2][k]+=x*wv.z; acc[3][k]+=x*wv.w;
                }
            }
            #pragma unroll
            for (int c = 0; c < 4; ++c)
            #pragma unroll
            for (int k = 0; k < 4; ++k)
                st_nt(&ob[(size_t)(cg*4+c)*HWp + pofs[k]], acc[c][k]);
        }
    }
}

extern "C" void kernel_launch(void* const* d_in, const int* in_sizes, int n_in,
                              void* d_out, int out_size, void* d_ws, size_t ws_size,
                              hipStream_t stream) {
    const float* f  = (const float*)d_in[0];
    const float* w1 = (const float*)d_in[1];
    const float* b1 = (const float*)d_in[2];
    const float* w2 = (const float*)d_in[3];
    const float* b2 = (const float*)d_in[4];
    const float* w3 = (const float*)d_in[5];
    const float* b3 = (const float*)d_in[6];
    const float* w4 = (const float*)d_in[7];
    const float* b4 = (const float*)d_in[8];
    float* out = (float*)d_out;
    float* ws  = (float*)d_ws;

    prep_weights<<<1, 256, 0, stream>>>(w2, b2, w3, b3, w4, b4, ws);
    dim3 grid(WW/TS, HH/TS, 8);
    enc_fused<<<grid, 256, 0, stream>>>(f, w1, b1, ws, out);
}